// Round 12
// baseline (203.005 us; speedup 1.0000x reference)
//
#include <hip/hip_runtime.h>
#include <math.h>

#define NT 2048
#define HS 64
#define HNN 256
#define NSTEPS 1000
#define TSTEP 0.01f

typedef unsigned short u16;
typedef __attribute__((ext_vector_type(8))) short bf16x8;
typedef __attribute__((ext_vector_type(4))) float f32x4;

// ws: only the bf16 frag region is used now
#define OFF_HT   148736    // YH (65536 floats worth) + YL

#define S_H 1028           // k_hidden LDS stage stride

// RNE f32 -> bf16 split: x ~= hi + lo (each bf16), err ~ 2^-18 |x|
__device__ inline void bsplit(float x, u16& hi, u16& lo) {
    unsigned u = __float_as_uint(x);
    unsigned r = (u + 0x7FFFu + ((u >> 16) & 1u)) >> 16;
    hi = (u16)r;
    float xh = __uint_as_float(r << 16);
    float d = x - xh;
    unsigned v = __float_as_uint(d);
    unsigned s = (v + 0x7FFFu + ((v >> 16) & 1u)) >> 16;
    lo = (u16)s;
}

__device__ inline void bar_lds() {
    asm volatile("s_waitcnt lgkmcnt(0)" ::: "memory");
    __builtin_amdgcn_s_barrier();
    asm volatile("" ::: "memory");
}

__device__ inline float tanh_fast(float x) {
    float xc = fminf(fmaxf(x, -15.f), 15.f);
    float a = __builtin_amdgcn_exp2f(xc * 2.885390082f);   // e^{2x}
    return (a - 1.f) * __builtin_amdgcn_rcpf(a + 1.f);
}

// ---------------- k_front: 128 blocks x 512 thr -----------------------------------
// Per block: (1) redundant no-pivot pipelined GJ -> R in LDS (parallel across CUs,
// wall time = single-block GJ), (2) hT -> x0 -> y=Rx0 -> 2x refinement, (3) MFMA
// frags -> ws, (4) acts for its 16 targets. Zero intermediate global round-trips.
struct FrontSh {
    union {
        float Aug[64 * 130];                       // GJ phase (33280 B)
        struct {
            union { float shT[256 * 17]; float rs[64 * 17]; float us[16 * 128]; } a;
            float x0s[64 * 17];
            float y0s[64 * 17];
        } p2;
    } u;
    float Rs[64 * 65];
    float fvec[2][64];
    float tgt[16][2];
    float lam_s[64], l2l_s[64];
    float Q_s[128];
};

__global__ __launch_bounds__(512) void k_front(const float* __restrict__ target,
                                               const float* __restrict__ l1_w,
                                               const float* __restrict__ l1_b,
                                               const float* __restrict__ l2_w,
                                               const float* __restrict__ l2_b,
                                               const float* __restrict__ lm_w,
                                               const float* __restrict__ lm_b,
                                               const float* __restrict__ D,
                                               const float* __restrict__ P,
                                               float* __restrict__ ws,
                                               float* __restrict__ actions) {
    __shared__ FrontSh sh;
    int ct = blockIdx.x;                 // 0..127
    int cbase = ct * 16;
    int tid = threadIdx.x;
    float* Aug = sh.u.Aug;

    for (int idx = tid; idx < 64 * 128; idx += 512) {
        int r = idx >> 7, c = idx & 127;
        Aug[r * 130 + c] = (c < 64) ? P[r * 64 + c] : ((c - 64) == r ? 1.f : 0.f);
    }
    __syncthreads();

    // prologue: fvec0 (tid<64) + small loads on other tid ranges
    if (tid < 64) {
        float nv = Aug[tid * 130];
        float pv = __shfl(nv, 0);
        sh.fvec[0][tid] = (tid == 0) ? 0.f : nv * __builtin_amdgcn_rcpf(pv);
    } else if (tid < 128) {
        int i = tid - 64;
        float l = 1.0f - TSTEP * expf(D[i]);
        sh.lam_s[i] = l;
        sh.l2l_s[i] = log2f(l);
    } else if (tid < 256) {
        int t = tid - 128;                     // Q[a][i] = sum_r lm_w[a][r] P[r][i]
        int a = t >> 6, i = t & 63;
        float s = 0.f;
        for (int r = 0; r < 64; ++r) s = fmaf(lm_w[a * 64 + r], P[r * 64 + i], s);
        sh.Q_s[t] = s;
    } else if (tid < 272) {
        int c = tid - 256;
        float2 tv = ((const float2*)target)[cbase + c];
        sh.tgt[c][0] = tv.x; sh.tgt[c][1] = tv.y;
    }
    __syncthreads();

    // no-pivot pipelined GJ: 1 barrier/iter
    for (int t = 0; t < 64; ++t) {
        int par = t & 1;
        if (tid < 64) {
            int col0 = (t < 63) ? (t + 1) : 64;
            float f = sh.fvec[par][tid];
            float src = Aug[t * 130 + col0];
            float nv = Aug[tid * 130 + col0] - f * src;
            Aug[tid * 130 + col0] = nv;
            if (t < 63) {
                float pv = __shfl(nv, t + 1);
                sh.fvec[par ^ 1][tid] = (tid == (t + 1)) ? 0.f
                                        : nv * __builtin_amdgcn_rcpf(pv);
            }
        } else {
            int w = (tid >> 6) - 1;                  // 0..6
            int lane = tid & 63;
            float f = sh.fvec[par][lane];
            const float* rowp = Aug + t * 130;
            float* rowr = Aug + lane * 130;
            int pcnt = 63 - t;
            for (int s = 1 + w; s < 64; s += 7) {
                int col = (s < pcnt) ? (t + 1 + s) : (64 + (s - pcnt));
                rowr[col] -= f * rowp[col];
            }
        }
        __syncthreads();
    }

    // extract R (deferred row scaling via rcp; refinement repairs the ulp noise)
    for (int idx = tid; idx < 4096; idx += 512) {
        int j = idx >> 6, m = idx & 63;
        sh.Rs[j * 65 + m] = Aug[j * 130 + 64 + m]
                            * __builtin_amdgcn_rcpf(Aug[j * 130 + j]);
    }
    __syncthreads();   // Aug dead beyond here (p2 aliases it)

    // hT row j = tid (<256), 16 local columns
    if (tid < 256) {
        float w0 = l1_w[2 * tid], w1 = l1_w[2 * tid + 1], bb = l1_b[tid];
        #pragma unroll
        for (int cc = 0; cc < 16; ++cc)
            sh.u.p2.a.shT[tid * 17 + cc] =
                fmaxf(fmaf(w0, sh.tgt[cc][0], fmaf(w1, sh.tgt[cc][1], bb)), 0.f);
    }
    __syncthreads();

    int i = tid >> 3, cs = (tid & 7) * 2;      // each thread: row i, 2 cols
    {   // x0[i][c] = l2_w[i,:] @ hT[:,c] + l2_b[i]
        const float* l2wi = l2_w + i * 256;
        float bb = l2_b[i];
        float a0 = bb, a1 = bb;
        #pragma unroll 4
        for (int j = 0; j < 256; ++j) {
            float w = l2wi[j];
            a0 = fmaf(w, sh.u.p2.a.shT[j * 17 + cs], a0);
            a1 = fmaf(w, sh.u.p2.a.shT[j * 17 + cs + 1], a1);
        }
        sh.u.p2.x0s[i * 17 + cs] = a0; sh.u.p2.x0s[i * 17 + cs + 1] = a1;
    }
    __syncthreads();

    const float* Ri = sh.Rs + i * 65;
    {   // y = R @ x0
        float b0 = 0, b1 = 0;
        #pragma unroll 4
        for (int m = 0; m < 64; ++m) {
            float rv = Ri[m];
            b0 = fmaf(rv, sh.u.p2.x0s[m * 17 + cs], b0);
            b1 = fmaf(rv, sh.u.p2.x0s[m * 17 + cs + 1], b1);
        }
        sh.u.p2.y0s[i * 17 + cs] = b0; sh.u.p2.y0s[i * 17 + cs + 1] = b1;
    }
    __syncthreads();

    // 2x iterative refinement: y += R (x0 - P y)   (rs aliases dead shT)
    const float* Pi = P + i * 64;
    #pragma unroll 1
    for (int it = 0; it < 2; ++it) {
        float r0 = sh.u.p2.x0s[i * 17 + cs], r1 = sh.u.p2.x0s[i * 17 + cs + 1];
        #pragma unroll 4
        for (int m = 0; m < 64; ++m) {
            float pv = Pi[m];
            r0 = fmaf(-pv, sh.u.p2.y0s[m * 17 + cs], r0);
            r1 = fmaf(-pv, sh.u.p2.y0s[m * 17 + cs + 1], r1);
        }
        __syncthreads();   // y0s reads done before rs overwrite ordering irrelevant (disjoint), but x0s/shT alias safety
        sh.u.p2.a.rs[i * 17 + cs] = r0; sh.u.p2.a.rs[i * 17 + cs + 1] = r1;
        __syncthreads();
        float d0 = 0, d1 = 0;
        #pragma unroll 4
        for (int m = 0; m < 64; ++m) {
            float rv = Ri[m];
            d0 = fmaf(rv, sh.u.p2.a.rs[m * 17 + cs], d0);
            d1 = fmaf(rv, sh.u.p2.a.rs[m * 17 + cs + 1], d1);
        }
        sh.u.p2.y0s[i * 17 + cs] += d0; sh.u.p2.y0s[i * 17 + cs + 1] += d1;
        __syncthreads();
    }

    // us[cg][t] = Q[t] * y0s[i(t)][cg]   (us aliases dead rs/shT)
    for (int idx = tid; idx < 2048; idx += 512) {
        int cgi = idx >> 7, t = idx & 127;
        sh.u.p2.a.us[cgi * 128 + t] = sh.Q_s[t] * sh.u.p2.y0s[(t & 63) * 17 + cgi];
    }
    // MFMA frags (layout k_hidden expects)
    if (tid < 128) {
        int kt = tid >> 6, lane = tid & 63;
        int c_l = lane & 15;
        int i0 = kt * 32 + (lane >> 4) * 8;
        u16* YH = (u16*)(ws + OFF_HT);
        u16* YL = YH + 131072;
        bf16x8 vh, vl;
        #pragma unroll
        for (int j = 0; j < 8; ++j) {
            u16 h, lo;
            bsplit(sh.u.p2.y0s[(i0 + j) * 17 + c_l], h, lo);
            vh[j] = (short)h; vl[j] = (short)lo;
        }
        int off = ((ct * 2 + kt) * 64 + lane);
        *(bf16x8*)(YH + off * 8) = vh;
        *(bf16x8*)(YL + off * 8) = vl;
    }
    __syncthreads();

    // acts: 500 threads, 2 k-values each, 4 chunks of 4 targets
    if (tid < 500) {
        int k0 = tid * 2;
        float b0 = lm_b[0], b1 = lm_b[1];
        float fk0 = (float)k0;
        #pragma unroll 1
        for (int ch = 0; ch < 4; ++ch) {
            int cg0 = ch * 4;
            float2 s[4][2];
            #pragma unroll
            for (int j = 0; j < 4; ++j) {
                s[j][0] = make_float2(b0, b0);
                s[j][1] = make_float2(b1, b1);
            }
            #pragma unroll 4
            for (int ii = 0; ii < 64; ++ii) {
                float p0 = __builtin_amdgcn_exp2f(fk0 * sh.l2l_s[ii]);
                float p1 = p0 * sh.lam_s[ii];
                #pragma unroll
                for (int j = 0; j < 4; ++j) {
                    float u0 = sh.u.p2.a.us[(cg0 + j) * 128 + ii];
                    float u1 = sh.u.p2.a.us[(cg0 + j) * 128 + 64 + ii];
                    s[j][0].x = fmaf(u0, p0, s[j][0].x);
                    s[j][0].y = fmaf(u0, p1, s[j][0].y);
                    s[j][1].x = fmaf(u1, p0, s[j][1].x);
                    s[j][1].y = fmaf(u1, p1, s[j][1].y);
                }
            }
            #pragma unroll
            for (int j = 0; j < 4; ++j)
                #pragma unroll
                for (int a = 0; a < 2; ++a) {
                    float2 r;
                    r.x = tanh_fast(s[j][a].x);
                    r.y = tanh_fast(s[j][a].y);
                    *(float2*)(actions + (size_t)(cbase + cg0 + j) * 2000 + a * 1000 + k0) = r;
                }
        }
    }
}

// ---------------- main: hidden[k] = (P diag(lam^k)) @ y0, split-bf16 MFMA --------
// identical to round 11 (~108 us)
__global__ __launch_bounds__(512, 2) void k_hidden(const float* __restrict__ P,
                                                   const float* __restrict__ D,
                                                   const float* __restrict__ ws,
                                                   float* __restrict__ hidden) {
    int k = blockIdx.x;
    int tid = threadIdx.x;
    int wid = tid >> 6, lane = tid & 63;
    int l15 = lane & 15, lg = lane >> 4;

    extern __shared__ float stage[];   // 16 * S_H floats = 65792 B
    __shared__ float lp_s[64];

    const u16* YH = (const u16*)(ws + OFF_HT);
    const u16* YL = YH + 131072;

    if (tid < 64) {
        float l = 1.0f - TSTEP * expf(D[tid]);
        lp_s[tid] = exp2f((float)k * log2f(l));
    }
    __syncthreads();

    bf16x8 ah[4][2], al[4][2];
    #pragma unroll
    for (int rt = 0; rt < 4; ++rt) {
        int r = rt * 16 + l15;
        #pragma unroll
        for (int kt = 0; kt < 2; ++kt) {
            int i0 = kt * 32 + lg * 8;
            #pragma unroll
            for (int j = 0; j < 8; ++j) {
                float v = P[r * 64 + i0 + j] * lp_s[i0 + j];
                u16 h, lo;
                bsplit(v, h, lo);
                ah[rt][kt][j] = (short)h;
                al[rt][kt][j] = (short)lo;
            }
        }
    }

    float* outk = hidden + (size_t)k * 64 * NT;

    #pragma unroll 1
    for (int half = 0; half < 2; ++half) {
        bf16x8 bh[8][2], bl[8][2];
        #pragma unroll
        for (int q = 0; q < 8; ++q)
            #pragma unroll
            for (int kt = 0; kt < 2; ++kt) {
                int ct_g = half * 64 + wid * 8 + q;
                int off = ((ct_g * 2 + kt) * 64 + lane) * 8;
                bh[q][kt] = *(const bf16x8*)(YH + off);
                bl[q][kt] = *(const bf16x8*)(YL + off);
            }
        #pragma unroll
        for (int rt = 0; rt < 4; ++rt) {
            #pragma unroll
            for (int q = 0; q < 8; ++q) {
                f32x4 acc = {0.f, 0.f, 0.f, 0.f};
                #pragma unroll
                for (int kt = 0; kt < 2; ++kt) {
                    acc = __builtin_amdgcn_mfma_f32_16x16x32_bf16(ah[rt][kt], bh[q][kt], acc, 0, 0, 0);
                    acc = __builtin_amdgcn_mfma_f32_16x16x32_bf16(al[rt][kt], bh[q][kt], acc, 0, 0, 0);
                    acc = __builtin_amdgcn_mfma_f32_16x16x32_bf16(ah[rt][kt], bl[q][kt], acc, 0, 0, 0);
                }
                int col = wid * 128 + q * 16 + l15;
                #pragma unroll
                for (int reg = 0; reg < 4; ++reg)
                    stage[(lg * 4 + reg) * S_H + col] = acc[reg];
            }
            bar_lds();
            #pragma unroll
            for (int it = 0; it < 8; ++it) {
                int f = it * 512 + tid;            // float4 index, 0..4095
                int r = f >> 8, c4 = f & 255;
                float4 v = *(const float4*)&stage[r * S_H + (c4 << 2)];
                *(float4*)(outk + (size_t)(rt * 16 + r) * NT + half * 1024 + (c4 << 2)) = v;
            }
            bar_lds();
        }
    }
}

extern "C" void kernel_launch(void* const* d_in, const int* in_sizes, int n_in,
                              void* d_out, int out_size, void* d_ws, size_t ws_size,
                              hipStream_t stream) {
    const float* target = (const float*)d_in[0];
    const float* D      = (const float*)d_in[1];
    const float* P      = (const float*)d_in[2];
    const float* l1_w   = (const float*)d_in[3];
    const float* l1_b   = (const float*)d_in[4];
    const float* l2_w   = (const float*)d_in[5];
    const float* l2_b   = (const float*)d_in[6];
    const float* lm_w   = (const float*)d_in[7];
    const float* lm_b   = (const float*)d_in[8];
    float* ws = (float*)d_ws;
    float* actions = (float*)d_out;                  // 2048*2*1000
    float* hidden  = (float*)d_out + 4096000;        // 1000*64*2048

    hipFuncSetAttribute((const void*)k_hidden,
                        hipFuncAttributeMaxDynamicSharedMemorySize, 16 * S_H * 4);

    hipLaunchKernelGGL(k_front,  dim3(128),  dim3(512), 0, stream,
                       target, l1_w, l1_b, l2_w, l2_b, lm_w, lm_b, D, P, ws, actions);
    hipLaunchKernelGGL(k_hidden, dim3(1000), dim3(512), 16 * S_H * 4, stream, P, D, ws, hidden);
}

// Round 13
// 185.219 us; speedup vs baseline: 1.0960x; 1.0960x over previous
//
#include <hip/hip_runtime.h>
#include <math.h>

#define NT 2048
#define HS 64
#define HNN 256
#define NSTEPS 1000
#define TSTEP 0.01f

typedef unsigned short u16;
typedef __attribute__((ext_vector_type(8))) short bf16x8;
typedef __attribute__((ext_vector_type(4))) float f32x4;

// ws: only the bf16 frag region is used
#define OFF_HT   148736    // YH (65536 floats worth) + YL

#define S_H 1028           // k_hidden LDS stage stride

// RNE f32 -> bf16 split: x ~= hi + lo (each bf16), err ~ 2^-18 |x|
__device__ inline void bsplit(float x, u16& hi, u16& lo) {
    unsigned u = __float_as_uint(x);
    unsigned r = (u + 0x7FFFu + ((u >> 16) & 1u)) >> 16;
    hi = (u16)r;
    float xh = __uint_as_float(r << 16);
    float d = x - xh;
    unsigned v = __float_as_uint(d);
    unsigned s = (v + 0x7FFFu + ((v >> 16) & 1u)) >> 16;
    lo = (u16)s;
}

__device__ inline void bar_lds() {
    asm volatile("s_waitcnt lgkmcnt(0)" ::: "memory");
    __builtin_amdgcn_s_barrier();
    asm volatile("" ::: "memory");
}

__device__ inline float tanh_fast(float x) {
    float xc = fminf(fmaxf(x, -15.f), 15.f);
    float a = __builtin_amdgcn_exp2f(xc * 2.885390082f);   // e^{2x}
    return (a - 1.f) * __builtin_amdgcn_rcpf(a + 1.f);
}

// ---------------- k_front: 256 blocks x 512 thr, 8 cols/block ---------------------
// Per block: redundant no-pivot GJ (wall time = 1 block; CUs are parallel), then
// hT -> x0 -> y=Rx0 -> 2x refinement -> frags -> acts for its 8 targets.
// 256 blocks => all 256 CUs work on the per-column phases (was 128).
struct FrontSh {
    union {
        float Aug[64 * 130];                       // GJ phase
        struct {
            union { float shT[256 * 17]; float rs[64 * 17]; float us[8 * 128]; } a;
            float x0s[64 * 17];
            float y0s[64 * 17];
        } p2;
    } u;
    float Rs[64 * 65];
    float fvec[2][64];
    float tgt[8][2];
    float lam_s[64], l2l_s[64];
    float Q_s[128];
};

__global__ __launch_bounds__(512) void k_front(const float* __restrict__ target,
                                               const float* __restrict__ l1_w,
                                               const float* __restrict__ l1_b,
                                               const float* __restrict__ l2_w,
                                               const float* __restrict__ l2_b,
                                               const float* __restrict__ lm_w,
                                               const float* __restrict__ lm_b,
                                               const float* __restrict__ D,
                                               const float* __restrict__ P,
                                               float* __restrict__ ws,
                                               float* __restrict__ actions) {
    __shared__ FrontSh sh;
    int ct = blockIdx.x;                 // 0..255
    int cbase = ct * 8;
    int tid = threadIdx.x;
    float* Aug = sh.u.Aug;

    for (int idx = tid; idx < 64 * 128; idx += 512) {
        int r = idx >> 7, c = idx & 127;
        Aug[r * 130 + c] = (c < 64) ? P[r * 64 + c] : ((c - 64) == r ? 1.f : 0.f);
    }
    __syncthreads();

    // prologue: fvec0 (tid<64) + small loads on other tid ranges
    if (tid < 64) {
        float nv = Aug[tid * 130];
        float pv = __shfl(nv, 0);
        sh.fvec[0][tid] = (tid == 0) ? 0.f : nv * __builtin_amdgcn_rcpf(pv);
    } else if (tid < 128) {
        int i = tid - 64;
        float l = 1.0f - TSTEP * expf(D[i]);
        sh.lam_s[i] = l;
        sh.l2l_s[i] = log2f(l);
    } else if (tid < 256) {
        int t = tid - 128;                     // Q[a][i] = sum_r lm_w[a][r] P[r][i]
        int a = t >> 6, i = t & 63;
        float s = 0.f;
        for (int r = 0; r < 64; ++r) s = fmaf(lm_w[a * 64 + r], P[r * 64 + i], s);
        sh.Q_s[t] = s;
    } else if (tid < 264) {
        int c = tid - 256;
        float2 tv = ((const float2*)target)[cbase + c];
        sh.tgt[c][0] = tv.x; sh.tgt[c][1] = tv.y;
    }
    __syncthreads();

    // no-pivot pipelined GJ: 1 barrier/iter
    for (int t = 0; t < 64; ++t) {
        int par = t & 1;
        if (tid < 64) {
            int col0 = (t < 63) ? (t + 1) : 64;
            float f = sh.fvec[par][tid];
            float src = Aug[t * 130 + col0];
            float nv = Aug[tid * 130 + col0] - f * src;
            Aug[tid * 130 + col0] = nv;
            if (t < 63) {
                float pv = __shfl(nv, t + 1);
                sh.fvec[par ^ 1][tid] = (tid == (t + 1)) ? 0.f
                                        : nv * __builtin_amdgcn_rcpf(pv);
            }
        } else {
            int w = (tid >> 6) - 1;                  // 0..6
            int lane = tid & 63;
            float f = sh.fvec[par][lane];
            const float* rowp = Aug + t * 130;
            float* rowr = Aug + lane * 130;
            int pcnt = 63 - t;
            for (int s = 1 + w; s < 64; s += 7) {
                int col = (s < pcnt) ? (t + 1 + s) : (64 + (s - pcnt));
                rowr[col] -= f * rowp[col];
            }
        }
        __syncthreads();
    }

    // extract R (deferred row scaling via rcp; refinement repairs the ulp noise)
    for (int idx = tid; idx < 4096; idx += 512) {
        int j = idx >> 6, m = idx & 63;
        sh.Rs[j * 65 + m] = Aug[j * 130 + 64 + m]
                            * __builtin_amdgcn_rcpf(Aug[j * 130 + j]);
    }
    __syncthreads();   // Aug dead beyond here (p2 aliases it)

    // hT row j = tid (<256), 8 local columns
    if (tid < 256) {
        float w0 = l1_w[2 * tid], w1 = l1_w[2 * tid + 1], bb = l1_b[tid];
        #pragma unroll
        for (int cc = 0; cc < 8; ++cc)
            sh.u.p2.a.shT[tid * 17 + cc] =
                fmaxf(fmaf(w0, sh.tgt[cc][0], fmaf(w1, sh.tgt[cc][1], bb)), 0.f);
    }
    __syncthreads();

    int i = tid >> 3, c = tid & 7;             // each thread: row i, ONE col
    {   // x0[i][c] = l2_w[i,:] @ hT[:,c] + l2_b[i]
        const float* l2wi = l2_w + i * 256;
        float a0 = l2_b[i], a1 = 0, a2 = 0, a3 = 0;
        #pragma unroll 4
        for (int j = 0; j < 256; j += 4) {
            a0 = fmaf(l2wi[j],     sh.u.p2.a.shT[j * 17 + c],       a0);
            a1 = fmaf(l2wi[j + 1], sh.u.p2.a.shT[(j + 1) * 17 + c], a1);
            a2 = fmaf(l2wi[j + 2], sh.u.p2.a.shT[(j + 2) * 17 + c], a2);
            a3 = fmaf(l2wi[j + 3], sh.u.p2.a.shT[(j + 3) * 17 + c], a3);
        }
        sh.u.p2.x0s[i * 17 + c] = (a0 + a1) + (a2 + a3);
    }
    __syncthreads();

    const float* Ri = sh.Rs + i * 65;
    {   // y = R @ x0
        float b0 = 0, b1 = 0;
        #pragma unroll 4
        for (int m = 0; m < 64; m += 2) {
            b0 = fmaf(Ri[m],     sh.u.p2.x0s[m * 17 + c],       b0);
            b1 = fmaf(Ri[m + 1], sh.u.p2.x0s[(m + 1) * 17 + c], b1);
        }
        sh.u.p2.y0s[i * 17 + c] = b0 + b1;
    }
    __syncthreads();

    // 2x iterative refinement: y += R (x0 - P y)   (rs aliases dead shT)
    const float* Pi = P + i * 64;
    #pragma unroll 1
    for (int it = 0; it < 2; ++it) {
        float r0 = sh.u.p2.x0s[i * 17 + c], r1 = 0;
        #pragma unroll 4
        for (int m = 0; m < 64; m += 2) {
            r0 = fmaf(-Pi[m],     sh.u.p2.y0s[m * 17 + c],       r0);
            r1 = fmaf(-Pi[m + 1], sh.u.p2.y0s[(m + 1) * 17 + c], r1);
        }
        __syncthreads();
        sh.u.p2.a.rs[i * 17 + c] = r0 + r1;
        __syncthreads();
        float d0 = 0, d1 = 0;
        #pragma unroll 4
        for (int m = 0; m < 64; m += 2) {
            d0 = fmaf(Ri[m],     sh.u.p2.a.rs[m * 17 + c],       d0);
            d1 = fmaf(Ri[m + 1], sh.u.p2.a.rs[(m + 1) * 17 + c], d1);
        }
        sh.u.p2.y0s[i * 17 + c] += d0 + d1;
        __syncthreads();
    }

    // us[cg][t] = Q[t] * y0s[i(t)][cg]   (us aliases dead rs/shT)
    for (int idx = tid; idx < 1024; idx += 512) {
        int cgi = idx >> 7, t = idx & 127;
        sh.u.p2.a.us[cgi * 128 + t] = sh.Q_s[t] * sh.u.p2.y0s[(t & 63) * 17 + cgi];
    }
    // MFMA frags: tile (ct>>1) spans two blocks; this block owns cols with
    // (lane&15)>>3 == (ct&1). Each lane writes its own disjoint 16B -> no race.
    if (tid < 128) {
        int kt = tid >> 6, lane = tid & 63;
        int c15 = lane & 15;
        if ((c15 >> 3) == (ct & 1)) {
            int cl = c15 & 7;
            int i0 = kt * 32 + (lane >> 4) * 8;
            u16* YH = (u16*)(ws + OFF_HT);
            u16* YL = YH + 131072;
            bf16x8 vh, vl;
            #pragma unroll
            for (int j = 0; j < 8; ++j) {
                u16 h, lo;
                bsplit(sh.u.p2.y0s[(i0 + j) * 17 + cl], h, lo);
                vh[j] = (short)h; vl[j] = (short)lo;
            }
            int off = (((ct >> 1) * 2 + kt) * 64 + lane);
            *(bf16x8*)(YH + off * 8) = vh;
            *(bf16x8*)(YL + off * 8) = vl;
        }
    }
    __syncthreads();

    // acts: 500 threads, 2 k-values each, all 8 targets; ii-outer hoists exp2
    if (tid < 500) {
        int k0 = tid * 2;
        float b0 = lm_b[0], b1 = lm_b[1];
        float fk0 = (float)k0;
        float2 s[8][2];
        #pragma unroll
        for (int j = 0; j < 8; ++j) {
            s[j][0] = make_float2(b0, b0);
            s[j][1] = make_float2(b1, b1);
        }
        #pragma unroll 2
        for (int ii = 0; ii < 64; ++ii) {
            float p0 = __builtin_amdgcn_exp2f(fk0 * sh.l2l_s[ii]);
            float p1 = p0 * sh.lam_s[ii];
            #pragma unroll
            for (int j = 0; j < 8; ++j) {
                float u0 = sh.u.p2.a.us[j * 128 + ii];
                float u1 = sh.u.p2.a.us[j * 128 + 64 + ii];
                s[j][0].x = fmaf(u0, p0, s[j][0].x);
                s[j][0].y = fmaf(u0, p1, s[j][0].y);
                s[j][1].x = fmaf(u1, p0, s[j][1].x);
                s[j][1].y = fmaf(u1, p1, s[j][1].y);
            }
        }
        #pragma unroll
        for (int j = 0; j < 8; ++j)
            #pragma unroll
            for (int a = 0; a < 2; ++a) {
                float2 r;
                r.x = tanh_fast(s[j][a].x);
                r.y = tanh_fast(s[j][a].y);
                *(float2*)(actions + (size_t)(cbase + j) * 2000 + a * 1000 + k0) = r;
            }
    }
}

// ---------------- main: hidden[k] = (P diag(lam^k)) @ y0, split-bf16 MFMA --------
// identical to rounds 11/12 (~108 us, practical plateau per 3-variant evidence)
__global__ __launch_bounds__(512, 2) void k_hidden(const float* __restrict__ P,
                                                   const float* __restrict__ D,
                                                   const float* __restrict__ ws,
                                                   float* __restrict__ hidden) {
    int k = blockIdx.x;
    int tid = threadIdx.x;
    int wid = tid >> 6, lane = tid & 63;
    int l15 = lane & 15, lg = lane >> 4;

    extern __shared__ float stage[];   // 16 * S_H floats = 65792 B
    __shared__ float lp_s[64];

    const u16* YH = (const u16*)(ws + OFF_HT);
    const u16* YL = YH + 131072;

    if (tid < 64) {
        float l = 1.0f - TSTEP * expf(D[tid]);
        lp_s[tid] = exp2f((float)k * log2f(l));
    }
    __syncthreads();

    bf16x8 ah[4][2], al[4][2];
    #pragma unroll
    for (int rt = 0; rt < 4; ++rt) {
        int r = rt * 16 + l15;
        #pragma unroll
        for (int kt = 0; kt < 2; ++kt) {
            int i0 = kt * 32 + lg * 8;
            #pragma unroll
            for (int j = 0; j < 8; ++j) {
                float v = P[r * 64 + i0 + j] * lp_s[i0 + j];
                u16 h, lo;
                bsplit(v, h, lo);
                ah[rt][kt][j] = (short)h;
                al[rt][kt][j] = (short)lo;
            }
        }
    }

    float* outk = hidden + (size_t)k * 64 * NT;

    #pragma unroll 1
    for (int half = 0; half < 2; ++half) {
        bf16x8 bh[8][2], bl[8][2];
        #pragma unroll
        for (int q = 0; q < 8; ++q)
            #pragma unroll
            for (int kt = 0; kt < 2; ++kt) {
                int ct_g = half * 64 + wid * 8 + q;
                int off = ((ct_g * 2 + kt) * 64 + lane) * 8;
                bh[q][kt] = *(const bf16x8*)(YH + off);
                bl[q][kt] = *(const bf16x8*)(YL + off);
            }
        #pragma unroll
        for (int rt = 0; rt < 4; ++rt) {
            #pragma unroll
            for (int q = 0; q < 8; ++q) {
                f32x4 acc = {0.f, 0.f, 0.f, 0.f};
                #pragma unroll
                for (int kt = 0; kt < 2; ++kt) {
                    acc = __builtin_amdgcn_mfma_f32_16x16x32_bf16(ah[rt][kt], bh[q][kt], acc, 0, 0, 0);
                    acc = __builtin_amdgcn_mfma_f32_16x16x32_bf16(al[rt][kt], bh[q][kt], acc, 0, 0, 0);
                    acc = __builtin_amdgcn_mfma_f32_16x16x32_bf16(ah[rt][kt], bl[q][kt], acc, 0, 0, 0);
                }
                int col = wid * 128 + q * 16 + l15;
                #pragma unroll
                for (int reg = 0; reg < 4; ++reg)
                    stage[(lg * 4 + reg) * S_H + col] = acc[reg];
            }
            bar_lds();
            #pragma unroll
            for (int it = 0; it < 8; ++it) {
                int f = it * 512 + tid;            // float4 index, 0..4095
                int r = f >> 8, c4 = f & 255;
                float4 v = *(const float4*)&stage[r * S_H + (c4 << 2)];
                *(float4*)(outk + (size_t)(rt * 16 + r) * NT + half * 1024 + (c4 << 2)) = v;
            }
            bar_lds();
        }
    }
}

extern "C" void kernel_launch(void* const* d_in, const int* in_sizes, int n_in,
                              void* d_out, int out_size, void* d_ws, size_t ws_size,
                              hipStream_t stream) {
    const float* target = (const float*)d_in[0];
    const float* D      = (const float*)d_in[1];
    const float* P      = (const float*)d_in[2];
    const float* l1_w   = (const float*)d_in[3];
    const float* l1_b   = (const float*)d_in[4];
    const float* l2_w   = (const float*)d_in[5];
    const float* l2_b   = (const float*)d_in[6];
    const float* lm_w   = (const float*)d_in[7];
    const float* lm_b   = (const float*)d_in[8];
    float* ws = (float*)d_ws;
    float* actions = (float*)d_out;                  // 2048*2*1000
    float* hidden  = (float*)d_out + 4096000;        // 1000*64*2048

    hipFuncSetAttribute((const void*)k_hidden,
                        hipFuncAttributeMaxDynamicSharedMemorySize, 16 * S_H * 4);

    hipLaunchKernelGGL(k_front,  dim3(256),  dim3(512), 0, stream,
                       target, l1_w, l1_b, l2_w, l2_b, lm_w, lm_b, D, P, ws, actions);
    hipLaunchKernelGGL(k_hidden, dim3(1000), dim3(512), 16 * S_H * 4, stream, P, D, ws, hidden);
}

// Round 14
// 164.512 us; speedup vs baseline: 1.2340x; 1.1259x over previous
//
#include <hip/hip_runtime.h>
#include <math.h>

#define NT 2048
#define HS 64
#define HNN 256
#define NSTEPS 1000
#define TSTEP 0.01f

typedef unsigned short u16;
typedef __attribute__((ext_vector_type(8))) short bf16x8;
typedef __attribute__((ext_vector_type(4))) float f32x4;

// ws: only the bf16 frag region is used
#define OFF_HT   148736    // YH (65536 floats worth) + YL

#define S_H 1028           // k_hidden LDS stage stride

// RNE f32 -> bf16 split: x ~= hi + lo (each bf16), err ~ 2^-18 |x|
__device__ inline void bsplit(float x, u16& hi, u16& lo) {
    unsigned u = __float_as_uint(x);
    unsigned r = (u + 0x7FFFu + ((u >> 16) & 1u)) >> 16;
    hi = (u16)r;
    float xh = __uint_as_float(r << 16);
    float d = x - xh;
    unsigned v = __float_as_uint(d);
    unsigned s = (v + 0x7FFFu + ((v >> 16) & 1u)) >> 16;
    lo = (u16)s;
}

__device__ inline void bar_lds() {
    asm volatile("s_waitcnt lgkmcnt(0)" ::: "memory");
    __builtin_amdgcn_s_barrier();
    asm volatile("" ::: "memory");
}

__device__ inline float tanh_fast(float x) {
    float xc = fminf(fmaxf(x, -15.f), 15.f);
    float a = __builtin_amdgcn_exp2f(xc * 2.885390082f);   // e^{2x}
    return (a - 1.f) * __builtin_amdgcn_rcpf(a + 1.f);
}

// ---------------- k_front: 256 blocks x 512 thr, 8 cols/block ---------------------
// DIRECT SOLVE: GJ elimination on the augmented [P | x0(8 cols)] (72 active cols,
// stride 73 => conflict-free). y0 = solve(P, x0) falls out directly -- no inverse
// extraction, no y=R@x0, no refinement. Redundant per block (CUs parallel).
struct FrontSh {
    float Aug[64 * 73];        // [P | x0] 18.7 KB
    float shT[256 * 9];        // hT for 8 cols
    float y0s[64 * 9];
    float fvec[2][64];
    float tgt[8][2];
    float lam_s[64], l2l_s[64];
    float Q_s[128];
    float us[8 * 128];
};

__global__ __launch_bounds__(512) void k_front(const float* __restrict__ target,
                                               const float* __restrict__ l1_w,
                                               const float* __restrict__ l1_b,
                                               const float* __restrict__ l2_w,
                                               const float* __restrict__ l2_b,
                                               const float* __restrict__ lm_w,
                                               const float* __restrict__ lm_b,
                                               const float* __restrict__ D,
                                               const float* __restrict__ P,
                                               float* __restrict__ ws,
                                               float* __restrict__ actions) {
    __shared__ FrontSh sh;
    int ct = blockIdx.x;                 // 0..255
    int cbase = ct * 8;
    int tid = threadIdx.x;

    // load P into Aug cols 0..63
    for (int idx = tid; idx < 4096; idx += 512) {
        int r = idx >> 6, c = idx & 63;
        sh.Aug[r * 73 + c] = P[r * 64 + c];
    }
    // small per-range prologue loads
    if (tid >= 448 && tid < 456) {
        int c = tid - 448;
        float2 tv = ((const float2*)target)[cbase + c];
        sh.tgt[c][0] = tv.x; sh.tgt[c][1] = tv.y;
    } else if (tid >= 256 && tid < 320) {
        int i = tid - 256;
        float l = 1.0f - TSTEP * expf(D[i]);
        sh.lam_s[i] = l;
        sh.l2l_s[i] = log2f(l);
    } else if (tid >= 320 && tid < 448) {
        int t = tid - 320;                     // Q[a][i] = sum_r lm_w[a][r] P[r][i]
        int a = t >> 6, i = t & 63;
        float s = 0.f;
        for (int r = 0; r < 64; ++r) s = fmaf(lm_w[a * 64 + r], P[r * 64 + i], s);
        sh.Q_s[t] = s;
    }
    __syncthreads();

    // hT row j = tid (<256), 8 local columns
    if (tid < 256) {
        float w0 = l1_w[2 * tid], w1 = l1_w[2 * tid + 1], bb = l1_b[tid];
        #pragma unroll
        for (int cc = 0; cc < 8; ++cc)
            sh.shT[tid * 9 + cc] =
                fmaxf(fmaf(w0, sh.tgt[cc][0], fmaf(w1, sh.tgt[cc][1], bb)), 0.f);
    }
    __syncthreads();

    int i = tid >> 3, c = tid & 7;             // each thread: row i, ONE col
    {   // x0[i][c] = l2_w[i,:] @ hT[:,c] + l2_b[i]  -> Aug cols 64..71
        const float* l2wi = l2_w + i * 256;
        float a0 = l2_b[i], a1 = 0, a2 = 0, a3 = 0;
        #pragma unroll 4
        for (int j = 0; j < 256; j += 4) {
            a0 = fmaf(l2wi[j],     sh.shT[j * 9 + c],       a0);
            a1 = fmaf(l2wi[j + 1], sh.shT[(j + 1) * 9 + c], a1);
            a2 = fmaf(l2wi[j + 2], sh.shT[(j + 2) * 9 + c], a2);
            a3 = fmaf(l2wi[j + 3], sh.shT[(j + 3) * 9 + c], a3);
        }
        sh.Aug[i * 73 + 64 + c] = (a0 + a1) + (a2 + a3);
    }
    // fvec0 while x0 settles
    if (tid < 64) {
        float nv = sh.Aug[tid * 73];
        float pv = __shfl(nv, 0);
        sh.fvec[0][tid] = (tid == 0) ? 0.f : nv * __builtin_amdgcn_rcpf(pv);
    }
    __syncthreads();

    // no-pivot pipelined GJ on [P | x0]: 1 barrier/iter, 64 iters
    for (int t = 0; t < 64; ++t) {
        int par = t & 1;
        if (tid < 64) {
            // wave0: update the next pivot column (or first RHS col at t=63)
            int col0 = (t < 63) ? (t + 1) : 64;
            float f = sh.fvec[par][tid];
            float src = sh.Aug[t * 73 + col0];
            float nv = sh.Aug[tid * 73 + col0] - f * src;
            sh.Aug[tid * 73 + col0] = nv;
            if (t < 63) {
                float pv = __shfl(nv, t + 1);
                sh.fvec[par ^ 1][tid] = (tid == (t + 1)) ? 0.f
                                        : nv * __builtin_amdgcn_rcpf(pv);
            }
        } else {
            // waves 1-7: remaining active cols = P {t+2..63} + RHS {64..71}\{col0}
            int w = (tid >> 6) - 1;                  // 0..6
            int lane = tid & 63;
            float f = sh.fvec[par][lane];
            const float* rowp = sh.Aug + t * 73;
            float* rowr = sh.Aug + lane * 73;
            int pcnt = 62 - t;                       // P-part count (-1 at t=63)
            int smax = pcnt + 8;                     // 7 at t=63
            for (int s = 1 + w; s <= smax; s += 7) {
                int col = (s <= pcnt) ? (t + 1 + s) : (64 + (s - pcnt - 1));
                rowr[col] -= f * rowp[col];
            }
        }
        __syncthreads();
    }

    // y0[i][c] = Aug[i][64+c] / Aug[i][i]
    sh.y0s[i * 9 + c] = sh.Aug[i * 73 + 64 + c]
                        * __builtin_amdgcn_rcpf(sh.Aug[i * 73 + i]);
    __syncthreads();

    // us[cg][t] = Q[t] * y0s[i(t)][cg]
    for (int idx = tid; idx < 1024; idx += 512) {
        int cgi = idx >> 7, t = idx & 127;
        sh.us[cgi * 128 + t] = sh.Q_s[t] * sh.y0s[(t & 63) * 9 + cgi];
    }
    // MFMA frags: tile (ct>>1) spans two blocks; this block owns cols with
    // (lane&15)>>3 == (ct&1). Each lane writes its own disjoint 16B -> no race.
    if (tid < 128) {
        int kt = tid >> 6, lane = tid & 63;
        int c15 = lane & 15;
        if ((c15 >> 3) == (ct & 1)) {
            int cl = c15 & 7;
            int i0 = kt * 32 + (lane >> 4) * 8;
            u16* YH = (u16*)(ws + OFF_HT);
            u16* YL = YH + 131072;
            bf16x8 vh, vl;
            #pragma unroll
            for (int j = 0; j < 8; ++j) {
                u16 h, lo;
                bsplit(sh.y0s[(i0 + j) * 9 + cl], h, lo);
                vh[j] = (short)h; vl[j] = (short)lo;
            }
            int off = (((ct >> 1) * 2 + kt) * 64 + lane);
            *(bf16x8*)(YH + off * 8) = vh;
            *(bf16x8*)(YL + off * 8) = vl;
        }
    }
    __syncthreads();

    // acts: 500 threads, 2 k-values each, all 8 targets; ii-outer hoists exp2
    if (tid < 500) {
        int k0 = tid * 2;
        float b0 = lm_b[0], b1 = lm_b[1];
        float fk0 = (float)k0;
        float2 s[8][2];
        #pragma unroll
        for (int j = 0; j < 8; ++j) {
            s[j][0] = make_float2(b0, b0);
            s[j][1] = make_float2(b1, b1);
        }
        #pragma unroll 2
        for (int ii = 0; ii < 64; ++ii) {
            float p0 = __builtin_amdgcn_exp2f(fk0 * sh.l2l_s[ii]);
            float p1 = p0 * sh.lam_s[ii];
            #pragma unroll
            for (int j = 0; j < 8; ++j) {
                float u0 = sh.us[j * 128 + ii];
                float u1 = sh.us[j * 128 + 64 + ii];
                s[j][0].x = fmaf(u0, p0, s[j][0].x);
                s[j][0].y = fmaf(u0, p1, s[j][0].y);
                s[j][1].x = fmaf(u1, p0, s[j][1].x);
                s[j][1].y = fmaf(u1, p1, s[j][1].y);
            }
        }
        #pragma unroll
        for (int j = 0; j < 8; ++j)
            #pragma unroll
            for (int a = 0; a < 2; ++a) {
                float2 r;
                r.x = tanh_fast(s[j][a].x);
                r.y = tanh_fast(s[j][a].y);
                *(float2*)(actions + (size_t)(cbase + j) * 2000 + a * 1000 + k0) = r;
            }
    }
}

// ---------------- main: hidden[k] = (P diag(lam^k)) @ y0, split-bf16 MFMA --------
// identical to rounds 11-13 (~108 us, practical plateau per 3-variant evidence)
__global__ __launch_bounds__(512, 2) void k_hidden(const float* __restrict__ P,
                                                   const float* __restrict__ D,
                                                   const float* __restrict__ ws,
                                                   float* __restrict__ hidden) {
    int k = blockIdx.x;
    int tid = threadIdx.x;
    int wid = tid >> 6, lane = tid & 63;
    int l15 = lane & 15, lg = lane >> 4;

    extern __shared__ float stage[];   // 16 * S_H floats = 65792 B
    __shared__ float lp_s[64];

    const u16* YH = (const u16*)(ws + OFF_HT);
    const u16* YL = YH + 131072;

    if (tid < 64) {
        float l = 1.0f - TSTEP * expf(D[tid]);
        lp_s[tid] = exp2f((float)k * log2f(l));
    }
    __syncthreads();

    bf16x8 ah[4][2], al[4][2];
    #pragma unroll
    for (int rt = 0; rt < 4; ++rt) {
        int r = rt * 16 + l15;
        #pragma unroll
        for (int kt = 0; kt < 2; ++kt) {
            int i0 = kt * 32 + lg * 8;
            #pragma unroll
            for (int j = 0; j < 8; ++j) {
                float v = P[r * 64 + i0 + j] * lp_s[i0 + j];
                u16 h, lo;
                bsplit(v, h, lo);
                ah[rt][kt][j] = (short)h;
                al[rt][kt][j] = (short)lo;
            }
        }
    }

    float* outk = hidden + (size_t)k * 64 * NT;

    #pragma unroll 1
    for (int half = 0; half < 2; ++half) {
        bf16x8 bh[8][2], bl[8][2];
        #pragma unroll
        for (int q = 0; q < 8; ++q)
            #pragma unroll
            for (int kt = 0; kt < 2; ++kt) {
                int ct_g = half * 64 + wid * 8 + q;
                int off = ((ct_g * 2 + kt) * 64 + lane) * 8;
                bh[q][kt] = *(const bf16x8*)(YH + off);
                bl[q][kt] = *(const bf16x8*)(YL + off);
            }
        #pragma unroll
        for (int rt = 0; rt < 4; ++rt) {
            #pragma unroll
            for (int q = 0; q < 8; ++q) {
                f32x4 acc = {0.f, 0.f, 0.f, 0.f};
                #pragma unroll
                for (int kt = 0; kt < 2; ++kt) {
                    acc = __builtin_amdgcn_mfma_f32_16x16x32_bf16(ah[rt][kt], bh[q][kt], acc, 0, 0, 0);
                    acc = __builtin_amdgcn_mfma_f32_16x16x32_bf16(al[rt][kt], bh[q][kt], acc, 0, 0, 0);
                    acc = __builtin_amdgcn_mfma_f32_16x16x32_bf16(ah[rt][kt], bl[q][kt], acc, 0, 0, 0);
                }
                int col = wid * 128 + q * 16 + l15;
                #pragma unroll
                for (int reg = 0; reg < 4; ++reg)
                    stage[(lg * 4 + reg) * S_H + col] = acc[reg];
            }
            bar_lds();
            #pragma unroll
            for (int it = 0; it < 8; ++it) {
                int f = it * 512 + tid;            // float4 index, 0..4095
                int r = f >> 8, c4 = f & 255;
                float4 v = *(const float4*)&stage[r * S_H + (c4 << 2)];
                *(float4*)(outk + (size_t)(rt * 16 + r) * NT + half * 1024 + (c4 << 2)) = v;
            }
            bar_lds();
        }
    }
}

extern "C" void kernel_launch(void* const* d_in, const int* in_sizes, int n_in,
                              void* d_out, int out_size, void* d_ws, size_t ws_size,
                              hipStream_t stream) {
    const float* target = (const float*)d_in[0];
    const float* D      = (const float*)d_in[1];
    const float* P      = (const float*)d_in[2];
    const float* l1_w   = (const float*)d_in[3];
    const float* l1_b   = (const float*)d_in[4];
    const float* l2_w   = (const float*)d_in[5];
    const float* l2_b   = (const float*)d_in[6];
    const float* lm_w   = (const float*)d_in[7];
    const float* lm_b   = (const float*)d_in[8];
    float* ws = (float*)d_ws;
    float* actions = (float*)d_out;                  // 2048*2*1000
    float* hidden  = (float*)d_out + 4096000;        // 1000*64*2048

    hipFuncSetAttribute((const void*)k_hidden,
                        hipFuncAttributeMaxDynamicSharedMemorySize, 16 * S_H * 4);

    hipLaunchKernelGGL(k_front,  dim3(256),  dim3(512), 0, stream,
                       target, l1_w, l1_b, l2_w, l2_b, lm_w, lm_b, D, P, ws, actions);
    hipLaunchKernelGGL(k_hidden, dim3(1000), dim3(512), 16 * S_H * 4, stream, P, D, ws, hidden);
}